// Round 16
// baseline (41.717 us; speedup 1.0000x reference)
//
#include <hip/hip_runtime.h>
#include <math.h>

// Segment mean via block-local counting sort + run-gather reduce.
//   BSHIFT=9: 196 buckets x 512 nodes (R13 optimum geometry).
//   K1: reg prefetch of dst+edge_x via NONTEMPORAL loads (read-once data,
//       keep LLC for pairs), LDS hist+scan (transposed boff_t), LDS
//       counting sort, dense uint4 writeout (cached -> LLC-resident for K2).
//   K2 (identical to R13): per-bucket block; 16-lane subgroup per run;
//       packed-double LDS accumulate (sum + 2^32*count in one atomic).
// Fallback to packed-f64-atomic scatter if ws is too small.

#define PACK_MAGIC 4294967296.0   // 2^32
#define NB 196                    // ceil(100000 / 512)
#define BSHIFT 9
#define SNODES 512
#define NC 512                    // chunks (= K1 blocks)
#define CMAXR 6400                // max chunkR staged in LDS (u32)
#define T1 1024                   // K1 block size (16 waves)
#define EPT 7                     // edges per thread: chunkR <= T1*EPT
#define T2 1024                   // K2 block size (64 subgroups of 16)

__device__ __forceinline__ unsigned pack_pair(float v, int local) {
    unsigned b = __float_as_uint(v);
    b = (b + 0x100u) & 0xFFFFFE00u;          // round mantissa to 14 bits
    return b | (unsigned)local;              // 9-bit intra-bucket index
}

// K1: reg prefetch -> hist -> scan(+boff_t store) -> LDS sort -> dense writeout
__global__ void __launch_bounds__(T1)
sort_kernel(const float* __restrict__ edge_x,
            const int* __restrict__ dst,
            unsigned* __restrict__ pairs,
            int* __restrict__ boff_t,        // [(NB+1)][NC] transposed
            int n_edges, int chunkR) {
    __shared__ unsigned s_data[CMAXR];
    __shared__ int h[NB];     // chunk bucket counts
    __shared__ int cnt[NB];   // cursors (start at exclusive-scan positions)

    int tid = threadIdx.x, blk = blockIdx.x;
    long beg = (long)blk * chunkR;
    long rem = (long)n_edges - beg;
    int chunkN = (rem < 0) ? 0 : (int)min((long)chunkR, rem);

    // prefetch ALL this thread's edges into registers, nontemporal
    // (read-once stream: don't let it evict the pairs working set)
    int   rd[EPT];
    float rv[EPT];
#pragma unroll
    for (int k = 0; k < EPT; ++k) {
        int i = tid + k * T1;
        bool ok = (i < chunkN);
        rd[k] = ok ? __builtin_nontemporal_load(dst + beg + i) : -1;
        rv[k] = ok ? __builtin_nontemporal_load(edge_x + (size_t)(beg + i) * 8)
                   : 0.0f;
    }

    for (int b = tid; b < NB; b += T1) h[b] = 0;
    __syncthreads();

    // histogram from registers
#pragma unroll
    for (int k = 0; k < EPT; ++k)
        if (rd[k] >= 0) atomicAdd(&h[rd[k] >> BSHIFT], 1);
    __syncthreads();

    // wave 0: exclusive scan h -> cnt, store transposed boff_t column
    if (tid < 64) {
        int lane = tid;
        const int K = (NB + 63) / 64;  // 4
        int vals[4];
        int local = 0;
#pragma unroll
        for (int k = 0; k < K; ++k) {
            int idx = lane * K + k;
            int v = (idx < NB) ? h[idx] : 0;
            vals[k] = v; local += v;
        }
        int s = local;
        for (int off = 1; off < 64; off <<= 1) {
            int t = __shfl_up(s, off);
            if (lane >= off) s += t;
        }
        int ex = s - local;
#pragma unroll
        for (int k = 0; k < K; ++k) {
            int idx = lane * K + k;
            if (idx < NB) { cnt[idx] = ex; boff_t[(size_t)idx * NC + blk] = ex; }
            ex += vals[k];
        }
        if (lane == 63) boff_t[(size_t)NB * NC + blk] = ex;   // total
    }
    __syncthreads();

    // stage into sorted LDS positions
#pragma unroll
    for (int k = 0; k < EPT; ++k) {
        if (rd[k] >= 0) {
            int b = rd[k] >> BSHIFT;
            int p = atomicAdd(&cnt[b], 1);
            s_data[p] = pack_pair(rv[k], rd[k] & (SNODES - 1));
        }
    }
    __syncthreads();

    // dense coalesced writeout (uint4), normal cached stores (K2 re-reads)
    unsigned* outp = pairs + (size_t)blk * chunkR;
    for (int p = tid * 4; p < chunkN; p += T1 * 4) {
        if (p + 4 <= chunkN) {
            *reinterpret_cast<uint4*>(outp + p) =
                *reinterpret_cast<const uint4*>(&s_data[p]);
        } else {
            for (int q = p; q < chunkN; ++q) outp[q] = s_data[q];
        }
    }
}

// K2: per-bucket block; 16-lane subgroup per run; packed-double LDS accumulate
__global__ void __launch_bounds__(T2)
reduce_kernel(const unsigned* __restrict__ pairs,
              const int* __restrict__ boff_t,
              float* __restrict__ out, int n_nodes, int chunkR) {
    __shared__ double acc[SNODES];
    __shared__ int s_lo[NC];
    __shared__ int s_hi[NC];

    int b = blockIdx.x, tid = threadIdx.x;
    for (int i = tid; i < SNODES; i += T2) acc[i] = 0.0;
    for (int c = tid; c < NC; c += T2) {          // dense transposed rows
        s_lo[c] = boff_t[(size_t)b * NC + c];
        s_hi[c] = boff_t[(size_t)(b + 1) * NC + c];
    }
    __syncthreads();

    int lane16 = tid & 15;
    int sub = tid >> 4;                           // 0..63
    for (int c = sub; c < NC; c += (T2 >> 4)) {
        int lo = s_lo[c], hi = s_hi[c];
        const unsigned* src = pairs + (size_t)c * chunkR;
        for (int j = lo + lane16; j < hi; j += 16) {
            unsigned p = src[j];
            float v = __uint_as_float(p & 0xFFFFFE00u);
            atomicAdd(&acc[p & 0x1FFu], (double)v + PACK_MAGIC);
        }
    }
    __syncthreads();

    int node0 = b << BSHIFT;
    for (int i = tid; i < SNODES; i += T2) {
        int node = node0 + i;
        if (node < n_nodes) {
            double x = acc[i];
            double c2 = nearbyint(x * (1.0 / PACK_MAGIC));
            double s2 = x - c2 * PACK_MAGIC;
            out[node] = (c2 > 0.0) ? (float)(s2 / c2) : 0.0f;
        }
    }
}

// ---------- fallback: packed-f64 atomic path ----------

__global__ void zero_ws_kernel(double* __restrict__ ws, int n) {
    int i = blockIdx.x * blockDim.x + threadIdx.x;
    int stride = gridDim.x * blockDim.x;
    for (; i < n; i += stride) ws[i] = 0.0;
}

__global__ void scatter_atomic_kernel(const float* __restrict__ edge_x,
                                      const int* __restrict__ dst,
                                      double* __restrict__ part,
                                      int n_edges, int n_nodes, int r_mask) {
    int t = blockIdx.x * blockDim.x + threadIdx.x;
    int basei = t * 4;
    double* my = part + (size_t)(blockIdx.x & r_mask) * (size_t)n_nodes;
    if (basei + 3 < n_edges) {
        int4 d4 = *reinterpret_cast<const int4*>(dst + basei);
        float v0 = edge_x[(size_t)(basei + 0) * 8];
        float v1 = edge_x[(size_t)(basei + 1) * 8];
        float v2 = edge_x[(size_t)(basei + 2) * 8];
        float v3 = edge_x[(size_t)(basei + 3) * 8];
        atomicAdd(&my[d4.x], (double)v0 + PACK_MAGIC);
        atomicAdd(&my[d4.y], (double)v1 + PACK_MAGIC);
        atomicAdd(&my[d4.z], (double)v2 + PACK_MAGIC);
        atomicAdd(&my[d4.w], (double)v3 + PACK_MAGIC);
    } else {
        for (int i = basei; i < n_edges; ++i) {
            float v = edge_x[(size_t)i * 8];
            atomicAdd(&my[dst[i]], (double)v + PACK_MAGIC);
        }
    }
}

__global__ void finalize_atomic_kernel(const double* __restrict__ part,
                                       float* __restrict__ out, int n_nodes, int R) {
    int i = blockIdx.x * blockDim.x + threadIdx.x;
    if (i >= n_nodes) return;
    double x = 0.0;
    for (int r = 0; r < R; ++r) x += part[(size_t)r * n_nodes + i];
    double c = nearbyint(x * (1.0 / PACK_MAGIC));
    double s = x - c * PACK_MAGIC;
    out[i] = (c > 0.0) ? (float)(s / c) : 0.0f;
}

// ---------- launch ----------

extern "C" void kernel_launch(void* const* d_in, const int* in_sizes, int n_in,
                              void* d_out, int out_size, void* d_ws, size_t ws_size,
                              hipStream_t stream) {
    const float* edge_x = (const float*)d_in[0];
    const int*   dst    = (const int*)d_in[1];
    float* out = (float*)d_out;

    const int n_nodes = out_size;        // 100000
    const int n_edges = in_sizes[1];     // 3200000

    // chunk rounded to multiple of 4 (uint4 writeout alignment)
    int chunkR = (((n_edges + NC - 1) / NC) + 3) & ~3;

    size_t pairs_bytes = (size_t)NC * chunkR * sizeof(unsigned);
    size_t bofft_bytes = (size_t)(NB + 1) * NC * sizeof(int);
    size_t need = pairs_bytes + bofft_bytes;

    if (ws_size >= need && n_nodes <= NB * SNODES &&
        chunkR <= CMAXR && chunkR <= T1 * EPT) {
        unsigned* pairs  = (unsigned*)d_ws;
        int*      boff_t = (int*)((char*)d_ws + pairs_bytes);

        sort_kernel<<<NC, T1, 0, stream>>>(edge_x, dst, pairs, boff_t,
                                           n_edges, chunkR);
        reduce_kernel<<<NB, T2, 0, stream>>>(pairs, boff_t, out,
                                             n_nodes, chunkR);
    } else {
        int R = 1;
        while (R < 8 && (size_t)(R * 2) * (size_t)n_nodes * sizeof(double) <= ws_size) R *= 2;
        double* part = (double*)d_ws;
        {
            int n = R * n_nodes;
            int blocks = min((n + 255) / 256, 2048);
            zero_ws_kernel<<<blocks, 256, 0, stream>>>(part, n);
        }
        {
            int nthreads = (n_edges + 3) / 4;
            int blocks = (nthreads + 255) / 256;
            scatter_atomic_kernel<<<blocks, 256, 0, stream>>>(edge_x, dst, part,
                                                              n_edges, n_nodes, R - 1);
        }
        {
            int blocks = (n_nodes + 255) / 256;
            finalize_atomic_kernel<<<blocks, 256, 0, stream>>>(part, out, n_nodes, R);
        }
    }
}

// Round 17
// 36.556 us; speedup vs baseline: 1.1412x; 1.1412x over previous
//
#include <hip/hip_runtime.h>
#include <math.h>

// Segment mean via block-local counting sort + run-gather reduce.
//   R13 configuration — established optimum across all explored axes:
//   BSHIFT {8,9,10} -> {53,36.7,38.9} us; grid-split 38.8; nontemporal 41.7.
//   BSHIFT=9: 196 buckets x 512 nodes; K2 runs avg 32 entries (128B).
//   K1: per-thread register prefetch of dst+edge_x (one exposed latency
//       round; cached loads so lanes share 128B edge_x lines), LDS
//       histogram + scan (TRANSPOSED boff_t from scan regs), LDS counting
//       sort, dense uint4 writeout.
//   K2: per-bucket block; 16-lane subgroup per chunk-run; packed-double
//       LDS accumulate (sum + 2^32*count in one atomic).
// Fallback to packed-f64-atomic scatter if ws is too small.

#define PACK_MAGIC 4294967296.0   // 2^32
#define NB 196                    // ceil(100000 / 512)
#define BSHIFT 9
#define SNODES 512
#define NC 512                    // chunks (= K1 blocks)
#define CMAXR 6400                // max chunkR staged in LDS (u32)
#define T1 1024                   // K1 block size (16 waves)
#define EPT 7                     // edges per thread: chunkR <= T1*EPT
#define T2 1024                   // K2 block size (64 subgroups of 16)

__device__ __forceinline__ unsigned pack_pair(float v, int local) {
    unsigned b = __float_as_uint(v);
    b = (b + 0x100u) & 0xFFFFFE00u;          // round mantissa to 14 bits
    return b | (unsigned)local;              // 9-bit intra-bucket index
}

// K1: reg prefetch -> hist -> scan(+boff_t store) -> LDS sort -> dense writeout
__global__ void __launch_bounds__(T1)
sort_kernel(const float* __restrict__ edge_x,
            const int* __restrict__ dst,
            unsigned* __restrict__ pairs,
            int* __restrict__ boff_t,        // [(NB+1)][NC] transposed
            int n_edges, int chunkR) {
    __shared__ unsigned s_data[CMAXR];
    __shared__ int h[NB];     // chunk bucket counts
    __shared__ int cnt[NB];   // cursors (start at exclusive-scan positions)

    int tid = threadIdx.x, blk = blockIdx.x;
    long beg = (long)blk * chunkR;
    long rem = (long)n_edges - beg;
    int chunkN = (rem < 0) ? 0 : (int)min((long)chunkR, rem);

    // prefetch ALL this thread's edges into registers (deep ILP, one round)
    int   rd[EPT];
    float rv[EPT];
#pragma unroll
    for (int k = 0; k < EPT; ++k) {
        int i = tid + k * T1;
        bool ok = (i < chunkN);
        rd[k] = ok ? dst[beg + i] : -1;
        rv[k] = ok ? edge_x[(size_t)(beg + i) * 8] : 0.0f;
    }

    for (int b = tid; b < NB; b += T1) h[b] = 0;
    __syncthreads();

    // histogram from registers
#pragma unroll
    for (int k = 0; k < EPT; ++k)
        if (rd[k] >= 0) atomicAdd(&h[rd[k] >> BSHIFT], 1);
    __syncthreads();

    // wave 0: exclusive scan h -> cnt, store transposed boff_t column
    if (tid < 64) {
        int lane = tid;
        const int K = (NB + 63) / 64;  // 4
        int vals[4];
        int local = 0;
#pragma unroll
        for (int k = 0; k < K; ++k) {
            int idx = lane * K + k;
            int v = (idx < NB) ? h[idx] : 0;
            vals[k] = v; local += v;
        }
        int s = local;
        for (int off = 1; off < 64; off <<= 1) {
            int t = __shfl_up(s, off);
            if (lane >= off) s += t;
        }
        int ex = s - local;
#pragma unroll
        for (int k = 0; k < K; ++k) {
            int idx = lane * K + k;
            if (idx < NB) { cnt[idx] = ex; boff_t[(size_t)idx * NC + blk] = ex; }
            ex += vals[k];
        }
        if (lane == 63) boff_t[(size_t)NB * NC + blk] = ex;   // total
    }
    __syncthreads();

    // stage into sorted LDS positions
#pragma unroll
    for (int k = 0; k < EPT; ++k) {
        if (rd[k] >= 0) {
            int b = rd[k] >> BSHIFT;
            int p = atomicAdd(&cnt[b], 1);
            s_data[p] = pack_pair(rv[k], rd[k] & (SNODES - 1));
        }
    }
    __syncthreads();

    // dense coalesced writeout (uint4)
    unsigned* outp = pairs + (size_t)blk * chunkR;
    for (int p = tid * 4; p < chunkN; p += T1 * 4) {
        if (p + 4 <= chunkN) {
            *reinterpret_cast<uint4*>(outp + p) =
                *reinterpret_cast<const uint4*>(&s_data[p]);
        } else {
            for (int q = p; q < chunkN; ++q) outp[q] = s_data[q];
        }
    }
}

// K2: per-bucket block; 16-lane subgroup per run; packed-double LDS accumulate
__global__ void __launch_bounds__(T2)
reduce_kernel(const unsigned* __restrict__ pairs,
              const int* __restrict__ boff_t,
              float* __restrict__ out, int n_nodes, int chunkR) {
    __shared__ double acc[SNODES];
    __shared__ int s_lo[NC];
    __shared__ int s_hi[NC];

    int b = blockIdx.x, tid = threadIdx.x;
    for (int i = tid; i < SNODES; i += T2) acc[i] = 0.0;
    for (int c = tid; c < NC; c += T2) {          // dense transposed rows
        s_lo[c] = boff_t[(size_t)b * NC + c];
        s_hi[c] = boff_t[(size_t)(b + 1) * NC + c];
    }
    __syncthreads();

    int lane16 = tid & 15;
    int sub = tid >> 4;                           // 0..63
    for (int c = sub; c < NC; c += (T2 >> 4)) {
        int lo = s_lo[c], hi = s_hi[c];
        const unsigned* src = pairs + (size_t)c * chunkR;
        for (int j = lo + lane16; j < hi; j += 16) {
            unsigned p = src[j];
            float v = __uint_as_float(p & 0xFFFFFE00u);
            atomicAdd(&acc[p & 0x1FFu], (double)v + PACK_MAGIC);
        }
    }
    __syncthreads();

    int node0 = b << BSHIFT;
    for (int i = tid; i < SNODES; i += T2) {
        int node = node0 + i;
        if (node < n_nodes) {
            double x = acc[i];
            double c2 = nearbyint(x * (1.0 / PACK_MAGIC));
            double s2 = x - c2 * PACK_MAGIC;
            out[node] = (c2 > 0.0) ? (float)(s2 / c2) : 0.0f;
        }
    }
}

// ---------- fallback: packed-f64 atomic path ----------

__global__ void zero_ws_kernel(double* __restrict__ ws, int n) {
    int i = blockIdx.x * blockDim.x + threadIdx.x;
    int stride = gridDim.x * blockDim.x;
    for (; i < n; i += stride) ws[i] = 0.0;
}

__global__ void scatter_atomic_kernel(const float* __restrict__ edge_x,
                                      const int* __restrict__ dst,
                                      double* __restrict__ part,
                                      int n_edges, int n_nodes, int r_mask) {
    int t = blockIdx.x * blockDim.x + threadIdx.x;
    int basei = t * 4;
    double* my = part + (size_t)(blockIdx.x & r_mask) * (size_t)n_nodes;
    if (basei + 3 < n_edges) {
        int4 d4 = *reinterpret_cast<const int4*>(dst + basei);
        float v0 = edge_x[(size_t)(basei + 0) * 8];
        float v1 = edge_x[(size_t)(basei + 1) * 8];
        float v2 = edge_x[(size_t)(basei + 2) * 8];
        float v3 = edge_x[(size_t)(basei + 3) * 8];
        atomicAdd(&my[d4.x], (double)v0 + PACK_MAGIC);
        atomicAdd(&my[d4.y], (double)v1 + PACK_MAGIC);
        atomicAdd(&my[d4.z], (double)v2 + PACK_MAGIC);
        atomicAdd(&my[d4.w], (double)v3 + PACK_MAGIC);
    } else {
        for (int i = basei; i < n_edges; ++i) {
            float v = edge_x[(size_t)i * 8];
            atomicAdd(&my[dst[i]], (double)v + PACK_MAGIC);
        }
    }
}

__global__ void finalize_atomic_kernel(const double* __restrict__ part,
                                       float* __restrict__ out, int n_nodes, int R) {
    int i = blockIdx.x * blockDim.x + threadIdx.x;
    if (i >= n_nodes) return;
    double x = 0.0;
    for (int r = 0; r < R; ++r) x += part[(size_t)r * n_nodes + i];
    double c = nearbyint(x * (1.0 / PACK_MAGIC));
    double s = x - c * PACK_MAGIC;
    out[i] = (c > 0.0) ? (float)(s / c) : 0.0f;
}

// ---------- launch ----------

extern "C" void kernel_launch(void* const* d_in, const int* in_sizes, int n_in,
                              void* d_out, int out_size, void* d_ws, size_t ws_size,
                              hipStream_t stream) {
    const float* edge_x = (const float*)d_in[0];
    const int*   dst    = (const int*)d_in[1];
    float* out = (float*)d_out;

    const int n_nodes = out_size;        // 100000
    const int n_edges = in_sizes[1];     // 3200000

    // chunk rounded to multiple of 4 (uint4 writeout alignment)
    int chunkR = (((n_edges + NC - 1) / NC) + 3) & ~3;

    size_t pairs_bytes = (size_t)NC * chunkR * sizeof(unsigned);
    size_t bofft_bytes = (size_t)(NB + 1) * NC * sizeof(int);
    size_t need = pairs_bytes + bofft_bytes;

    if (ws_size >= need && n_nodes <= NB * SNODES &&
        chunkR <= CMAXR && chunkR <= T1 * EPT) {
        unsigned* pairs  = (unsigned*)d_ws;
        int*      boff_t = (int*)((char*)d_ws + pairs_bytes);

        sort_kernel<<<NC, T1, 0, stream>>>(edge_x, dst, pairs, boff_t,
                                           n_edges, chunkR);
        reduce_kernel<<<NB, T2, 0, stream>>>(pairs, boff_t, out,
                                             n_nodes, chunkR);
    } else {
        int R = 1;
        while (R < 8 && (size_t)(R * 2) * (size_t)n_nodes * sizeof(double) <= ws_size) R *= 2;
        double* part = (double*)d_ws;
        {
            int n = R * n_nodes;
            int blocks = min((n + 255) / 256, 2048);
            zero_ws_kernel<<<blocks, 256, 0, stream>>>(part, n);
        }
        {
            int nthreads = (n_edges + 3) / 4;
            int blocks = (nthreads + 255) / 256;
            scatter_atomic_kernel<<<blocks, 256, 0, stream>>>(edge_x, dst, part,
                                                              n_edges, n_nodes, R - 1);
        }
        {
            int blocks = (n_nodes + 255) / 256;
            finalize_atomic_kernel<<<blocks, 256, 0, stream>>>(part, out, n_nodes, R);
        }
    }
}